// Round 5
// baseline (97.508 us; speedup 1.0000x reference)
//
#include <hip/hip_runtime.h>

#define DEV __device__ __forceinline__

typedef __attribute__((ext_vector_type(8)))  short bf16x8;
typedef __attribute__((ext_vector_type(4)))  short s16x4;
typedef __attribute__((ext_vector_type(16))) float f32x16;

constexpr int SB = 2;            // batch
constexpr int SS = 4096;         // seq len
constexpr int SH = 256;          // hidden
constexpr int NHEAD = 8, HD = 32;
constexpr int M_TOK = SB * SS;   // 8192 token rows
constexpr int NQKV = 3 * SH;     // 768
constexpr int NSPL = 4;          // kv split factor

// ---- workspace layout (bytes) ----
constexpr size_t OFF_CNT  = 0;                                 // int[2] padded counts
constexpr size_t OFF_BIAS = 256;                               // spare
constexpr size_t OFF_XB   = OFF_BIAS + 32768;                  // bf16[8192*256]; later Kc
constexpr size_t OFF_WQKV = OFF_XB + (size_t)M_TOK * SH * 2;   // bf16[768*256]; later idxC/biasC
constexpr size_t OFF_BQKV = OFF_WQKV + (size_t)NQKV * SH * 2;  // f32[768] (pad 4096)
constexpr size_t OFF_WOB  = OFF_BQKV + 4096;                   // bf16[256*256]
constexpr size_t OFF_BO   = OFF_WOB + (size_t)SH * SH * 2;     // f32[256] (pad 1024)
constexpr size_t OFF_Q    = OFF_BO + 1024;                     // bf16 [16][4096][32]
constexpr size_t OFF_K    = OFF_Q + (size_t)M_TOK * SH * 2;    // K; later OP0/Ow
constexpr size_t OFF_V    = OFF_K + (size_t)M_TOK * SH * 2;    // V row-major; later OP1
constexpr size_t OFF_VT   = OFF_V + (size_t)M_TOK * SH * 2;    // bf16 [16][32][4096] (compacted)
constexpr size_t OFF_O    = OFF_VT + (size_t)M_TOK * SH * 2;   // f32 Lp[4][16][4096] (1MB of 4MB)
constexpr size_t OFF_OP2  = OFF_O + (size_t)M_TOK * SH * 2;    // bf16[8192*256] partial 2
constexpr size_t OFF_OP3  = OFF_OP2 + (size_t)M_TOK * SH * 2;  // bf16[8192*256] partial 3
constexpr size_t WS_NEED  = OFF_OP3 + (size_t)M_TOK * SH * 2;

// ---- helpers ----
DEV short f2bf(float f) {                      // RNE f32 -> bf16 bits
  unsigned u = __builtin_bit_cast(unsigned, f);
  u = (u + 0x7FFFu + ((u >> 16) & 1u)) >> 16;
  return (short)u;
}

DEV float bf2f(short s) {
  return __builtin_bit_cast(float, ((unsigned)(unsigned short)s) << 16);
}

DEV float exp2_(float x) {
#if __has_builtin(__builtin_amdgcn_exp2f)
  return __builtin_amdgcn_exp2f(x);
#else
  float r;
  asm("v_exp_f32 %0, %1\n\ts_nop 0" : "=v"(r) : "v"(x));
  return r;
#endif
}

DEV unsigned cvtpk(float lo, float hi) {       // {bf16(lo), bf16(hi)} packed
  unsigned r;
  asm("v_cvt_pk_bf16_f32 %0, %1, %2" : "=v"(r) : "v"(lo), "v"(hi));
  return r;
}

DEV void plswap(unsigned& a, unsigned& b) {    // v_permlane32_swap_b32 a, b
  asm("v_permlane32_swap_b32 %0, %1" : "+v"(a), "+v"(b));
}

// ---- 1. weight/activation prep (f32 -> bf16, fold log2e/sqrt(d) into Q) ----
__global__ void prep_kernel(const float* __restrict__ x,
    const float* __restrict__ wq, const float* __restrict__ bq,
    const float* __restrict__ wk, const float* __restrict__ bk,
    const float* __restrict__ wv, const float* __restrict__ bv,
    const float* __restrict__ wo, const float* __restrict__ bo,
    short* __restrict__ xb, short* __restrict__ Wqkv, float* __restrict__ bqkv,
    short* __restrict__ wob, float* __restrict__ bof) {
  const float QS = (float)(1.4426950408889634 / 5.656854249492381);  // log2(e)/sqrt(32)
  long i = (long)blockIdx.x * 256 + threadIdx.x;
  const long NX = (long)M_TOK * SH;
  const long NW = (long)NQKV * SH;
  if (i < NX) { xb[i] = f2bf(x[i]); return; }
  i -= NX;
  if (i < NW) {
    int n = (int)(i >> 8), kk = (int)(i & 255);
    int tn = n >> 8, rr = n & 255;
    const float* src = tn == 0 ? wq : (tn == 1 ? wk : wv);
    float sc = tn == 0 ? QS : 1.f;
    Wqkv[i] = f2bf(src[rr * 256 + kk] * sc);
    return;
  }
  i -= NW;
  if (i < NQKV) {
    int n = (int)i, tn = n >> 8, rr = n & 255;
    const float* src = tn == 0 ? bq : (tn == 1 ? bk : bv);
    float sc = tn == 0 ? QS : 1.f;
    bqkv[n] = src[rr] * sc;
    return;
  }
  i -= NQKV;
  if (i < (long)SH * SH) { wob[i] = f2bf(wo[i]); return; }
  i -= (long)SH * SH;
  if (i < SH) bof[i] = bo[i];
}

// ---- 2/7. GEMM  C[m,n] = sum_k A[m,k]*B[n,k] + bias[n] ----
template <int MODE>
__global__ __launch_bounds__(256) void gemm_kernel(
    const short* __restrict__ Ag, const short* __restrict__ Bg,
    const float* __restrict__ bias,
    short* __restrict__ q, short* __restrict__ k, short* __restrict__ v,
    float* __restrict__ outf) {
  __shared__ __align__(16) short lA[8192];   // granule-major [kg 0..7][m 0..127] x8
  __shared__ __align__(16) short lB[4096];   // [kg 0..7][n 0..63] x8
  const int tid = threadIdx.x;
  const int lane = tid & 63, w = tid >> 6;
  const int wm = w >> 1, wn = w & 1;
  const int hi = lane >> 5, l31 = lane & 31;
  const int mb = blockIdx.x, nb = blockIdx.y;
  f32x16 acc0, acc1;
#pragma unroll
  for (int i = 0; i < 16; ++i) { acc0[i] = 0.f; acc1[i] = 0.f; }
  bf16x8 ra[4], rb[2];
  const int am = tid >> 3, ak = tid & 7;
  auto gload = [&](int kb) {
#pragma unroll
    for (int p = 0; p < 4; ++p)
      ra[p] = *(const bf16x8*)(Ag + (size_t)(mb * 128 + p * 32 + am) * 256 + kb * 64 + ak * 8);
#pragma unroll
    for (int p = 0; p < 2; ++p)
      rb[p] = *(const bf16x8*)(Bg + (size_t)(nb * 64 + p * 32 + am) * 256 + kb * 64 + ak * 8);
  };
  gload(0);
  for (int kb = 0; kb < 4; ++kb) {
    __syncthreads();
#pragma unroll
    for (int p = 0; p < 4; ++p)
      *(bf16x8*)(lA + (ak * 128 + p * 32 + am) * 8) = ra[p];
#pragma unroll
    for (int p = 0; p < 2; ++p)
      *(bf16x8*)(lB + (ak * 64 + p * 32 + am) * 8) = rb[p];
    __syncthreads();
    if (kb < 3) gload(kb + 1);
#pragma unroll
    for (int ks = 0; ks < 4; ++ks) {
      bf16x8 af0 = *(const bf16x8*)(lA + ((2 * ks + hi) * 128 + wm * 64 + l31) * 8);
      bf16x8 af1 = *(const bf16x8*)(lA + ((2 * ks + hi) * 128 + wm * 64 + 32 + l31) * 8);
      bf16x8 bf  = *(const bf16x8*)(lB + ((2 * ks + hi) * 64 + wn * 32 + l31) * 8);
      acc0 = __builtin_amdgcn_mfma_f32_32x32x16_bf16(af0, bf, acc0, 0, 0, 0);
      acc1 = __builtin_amdgcn_mfma_f32_32x32x16_bf16(af1, bf, acc1, 0, 0, 0);
    }
  }
  const int ncol = nb * 64 + wn * 32 + l31;
  const float bval = bias[ncol];
  if (MODE == 0) {
    const int tensor = nb >> 2;                       // 0=Q 1=K 2=V
    short* dst = tensor == 0 ? q : (tensor == 1 ? k : v);
    const int a = (nb & 3) * 64 + wn * 32 + l31;
    const int hh = a >> 5, d = a & 31;
#pragma unroll
    for (int mt = 0; mt < 2; ++mt) {
      const f32x16& acc = mt == 0 ? acc0 : acc1;
#pragma unroll
      for (int r = 0; r < 16; ++r) {
        int gm = mb * 128 + wm * 64 + mt * 32 + (r & 3) + 8 * (r >> 2) + 4 * hi;
        int bb = gm >> 12, ss = gm & 4095;
        dst[(((size_t)bb * NHEAD + hh) * SS + ss) * HD + d] = f2bf(acc[r] + bval);
      }
    }
  } else {
#pragma unroll
    for (int mt = 0; mt < 2; ++mt) {
      const f32x16& acc = mt == 0 ? acc0 : acc1;
#pragma unroll
      for (int r = 0; r < 16; ++r) {
        int gm = mb * 128 + wm * 64 + mt * 32 + (r & 3) + 8 * (r >> 2) + 4 * hi;
        outf[(size_t)gm * SH + ncol] = acc[r] + bval;
      }
    }
  }
}

// ---- 3. mask scan: detect encoding, stable prefix-scan -> compacted index list ----
// pads count to multiple of 256 so NSPL=4 quarters stay multiples of 64
__global__ void scan_mask_kernel(const unsigned char* __restrict__ m,
                                 int* __restrict__ idxC, float* __restrict__ biasC,
                                 int* __restrict__ cnts) {
  __shared__ int f_mis, f_off4, f_3f;
  __shared__ int ts[256];
  const int tid = threadIdx.x, b = blockIdx.x;
  if (tid == 0) { f_mis = 0; f_off4 = 0; f_3f = 0; }
  __syncthreads();
  int lm = 0, lo4 = 0, l3f = 0;
  for (int i = tid; i < 8192; i += 256) {
    unsigned char c = m[i];
    if (c) {
      if (i & 3) lm = 1;
      if ((i & 7) == 4) lo4 = 1;
      if ((i & 3) == 3 && c == 0x3F) l3f = 1;
    }
  }
  if (lm)  atomicOr(&f_mis, 1);
  if (lo4) atomicOr(&f_off4, 1);
  if (l3f) atomicOr(&f_3f, 1);
  __syncthreads();
  const int f = !f_mis ? (f_off4 ? 1 : 3) : (f_3f ? 2 : 0);  // 0=u8 1=i32 2=f32 3=i64
  int bits = 0;
  const int rbase = b * 4096 + tid * 16;
#pragma unroll
  for (int j = 0; j < 16; ++j) {
    int r = rbase + j;
    bool on;
    if (f == 0)      on = m[r] != 0;
    else if (f == 1) on = m[(size_t)r * 4] != 0;
    else if (f == 2) on = m[(size_t)r * 4 + 3] != 0;
    else             on = m[(size_t)r * 8] != 0;
    bits |= (int)on << j;
  }
  const int cnt = __popc(bits);
  ts[tid] = cnt;
  __syncthreads();
  for (int off = 1; off < 256; off <<= 1) {
    int u = (tid >= off) ? ts[tid - off] : 0;
    __syncthreads();
    ts[tid] += u;
    __syncthreads();
  }
  const int total = ts[255];
  int pos = ts[tid] - cnt;   // exclusive
  int* idxB = idxC + b * 4096;
  float* biasB = biasC + b * 4096;
  if (total == 0) {
    // all masked: softmax is shift-invariant -> identical to unmasked softmax
    for (int j = tid; j < 4096; j += 256) { idxB[j] = j; biasB[j] = 0.f; }
    if (tid == 0) cnts[b] = 4096;
    return;
  }
#pragma unroll
  for (int j = 0; j < 16; ++j)
    if ((bits >> j) & 1) { idxB[pos] = tid * 16 + j; biasB[pos] = 0.f; ++pos; }
  int cntpad = (total + 255) & ~255;
  if (cntpad < 256) cntpad = 256;
  for (int j = total + tid; j < cntpad; j += 256) { idxB[j] = -1; biasB[j] = -100000.f; }
  if (tid == 0) cnts[b] = cntpad;
}

// ---- 4. gather compacted K rows only (pad rows = 0); V handled by transpose ----
__global__ __launch_bounds__(256) void gather_k_kernel(const short* __restrict__ K,
    const int* __restrict__ idxC, const int* __restrict__ cnts,
    short* __restrict__ Kc) {
  const int bh = blockIdx.y, b = bh >> 3;
  const int jb = blockIdx.x * 64;
  if (jb >= cnts[b]) return;
  const int tid = threadIdx.x;
  const int j = jb + (tid >> 2), g = tid & 3;
  const int ix = idxC[b * 4096 + j];
  bf16x8 kv_{};
  if (ix >= 0) kv_ = *(const bf16x8*)(K + ((size_t)bh * SS + ix) * HD + g * 8);
  *(bf16x8*)(Kc + ((size_t)bh * SS + j) * HD + g * 8) = kv_;
}

// ---- 5. V transpose with fused gather: V[bh][idx][32] -> Vt[bh][32][j] ----
__global__ __launch_bounds__(256) void transpose_v_kernel(const short* __restrict__ V,
    const int* __restrict__ idxC, const int* __restrict__ cnts,
    short* __restrict__ Vt) {
  const int bh = blockIdx.x, b = bh >> 3, sbase = blockIdx.y * 64;
  if (sbase >= cnts[b]) return;
  __shared__ short t[64][33];
  const int tid = threadIdx.x;
  {
    int s = tid >> 2, g = tid & 3;
    int ix = idxC[b * 4096 + sbase + s];
    bf16x8 val{};
    if (ix >= 0) val = *(const bf16x8*)(V + ((size_t)bh * SS + ix) * HD + g * 8);
#pragma unroll
    for (int j = 0; j < 8; ++j) t[s][g * 8 + j] = val[j];
  }
  __syncthreads();
  {
    int d = tid >> 3, gs = tid & 7;
    bf16x8 out;
#pragma unroll
    for (int j = 0; j < 8; ++j) out[j] = t[gs * 8 + j][d];
    *(bf16x8*)(Vt + ((size_t)bh * HD + d) * SS + sbase + gs * 8) = out;
  }
}

// ---- 6. flash attention over compacted kv, split x4, KVBLK=64 ----
// Round-4 VERIFIED loop structure (single-buffer, 2 barriers/tile); only the
// split indexing (half -> quarter) changed. Occupancy comes from the grid.
__global__ __launch_bounds__(256, 4) void attn_kernel(const short* __restrict__ Q,
    const short* __restrict__ Kc, const short* __restrict__ Vt,
    const float* __restrict__ biasC, const int* __restrict__ cnts,
    short* __restrict__ OP0, short* __restrict__ OP1,
    short* __restrict__ OP2, short* __restrict__ OP3, float* __restrict__ Lp) {
  __shared__ __align__(16) short sK[4096];   // [gd 0..3][kv 0..63] x8
  __shared__ __align__(16) short sV[4096];   // [gkv 0..7][d 0..31] x8
  __shared__ __align__(16) float sB[64];
  const int tid = threadIdx.x;
  const int lane = tid & 63, wave = tid >> 6;
  const int hi = lane >> 5, l31 = lane & 31;
  const int qblk = blockIdx.x, bh = blockIdx.y, part = blockIdx.z;
  const int b = bh >> 3, h = bh & 7;
  const int Lq = cnts[b] >> 2;          // multiple of 64
  const int NIT = Lq >> 6;
  const int kv0 = part * Lq;
  const short* Kb = Kc + ((size_t)bh * SS + kv0) * HD;
  const short* Vb = Vt + (size_t)bh * HD * SS + kv0;
  const float* biasB = biasC + b * SS + kv0;
  const int qbase = qblk * 128 + wave * 32;
  const short* Qrow = Q + ((size_t)bh * SS + qbase + l31) * HD;
  const bf16x8 qf0 = *(const bf16x8*)(Qrow + hi * 8);
  const bf16x8 qf1 = *(const bf16x8*)(Qrow + 16 + hi * 8);
  bf16x8 ones;
#pragma unroll
  for (int j = 0; j < 8; ++j) ones[j] = (short)0x3F80;   // bf16 1.0
  f32x16 accO, lacc;
#pragma unroll
  for (int i = 0; i < 16; ++i) { accO[i] = 0.f; lacc[i] = 0.f; }
  // staging roles: every thread stages one K granule and one V granule
  const int kvs = tid >> 2, gd = tid & 3;
  const int dv = tid >> 3, gkv = tid & 7;
  const short* kvsrc = Kb + (size_t)kvs * HD + gd * 8;
  const short* vvsrc = Vb + (size_t)dv * SS + gkv * 8;
  short* kdst = sK + ((size_t)gd * 64 + kvs) * 8;
  short* vdst = sV + ((size_t)gkv * 32 + dv) * 8;
  bf16x8 stgK = *(const bf16x8*)kvsrc;
  bf16x8 stgV = *(const bf16x8*)vvsrc;
  float stgb = (tid < 64) ? biasB[tid] : 0.f;

  for (int kt = 0; kt < NIT; ++kt) {
    __syncthreads();
    *(bf16x8*)kdst = stgK;
    *(bf16x8*)vdst = stgV;
    if (tid < 64) sB[tid] = stgb;
    __syncthreads();
    if (kt + 1 < NIT) {
      stgK = *(const bf16x8*)(kvsrc + (size_t)(kt + 1) * 64 * HD);
      stgV = *(const bf16x8*)(vvsrc + (kt + 1) * 64);
      if (tid < 64) stgb = biasB[(kt + 1) * 64 + tid];
    }
    // C-init scores with mask bias (masked/pad -> -1e5 -> exp2 == 0)
    const float4* bp4 = (const float4*)sB;
    f32x16 s0, s1;
#pragma unroll
    for (int qd = 0; qd < 4; ++qd) {
      float4 f0 = bp4[2 * qd + hi];
      float4 f1 = bp4[8 + 2 * qd + hi];
      s0[4 * qd + 0] = f0.x; s0[4 * qd + 1] = f0.y; s0[4 * qd + 2] = f0.z; s0[4 * qd + 3] = f0.w;
      s1[4 * qd + 0] = f1.x; s1[4 * qd + 1] = f1.y; s1[4 * qd + 2] = f1.z; s1[4 * qd + 3] = f1.w;
    }
    const bf16x8 a00 = *(const bf16x8*)(sK + ((hi)*64 + l31) * 8);
    const bf16x8 a01 = *(const bf16x8*)(sK + ((2 + hi) * 64 + l31) * 8);
    const bf16x8 a10 = *(const bf16x8*)(sK + ((hi)*64 + 32 + l31) * 8);
    const bf16x8 a11 = *(const bf16x8*)(sK + ((2 + hi) * 64 + 32 + l31) * 8);
    s0 = __builtin_amdgcn_mfma_f32_32x32x16_bf16(a00, qf0, s0, 0, 0, 0);
    s0 = __builtin_amdgcn_mfma_f32_32x32x16_bf16(a01, qf1, s0, 0, 0, 0);
    s1 = __builtin_amdgcn_mfma_f32_32x32x16_bf16(a10, qf0, s1, 0, 0, 0);
    s1 = __builtin_amdgcn_mfma_f32_32x32x16_bf16(a11, qf1, s1, 0, 0, 0);
    // kv block 0 (kv 0..31 of tile)
    f32x16 p;
#pragma unroll
    for (int r = 0; r < 16; ++r) p[r] = exp2_(s0[r]);
    bf16x8 pa1, pa2;
    {
      unsigned a0 = cvtpk(p[0], p[1]),   a1 = cvtpk(p[2], p[3]);
      unsigned b0 = cvtpk(p[4], p[5]),   b1 = cvtpk(p[6], p[7]);
      plswap(a0, b0); plswap(a1, b1);
      unsigned c0 = cvtpk(p[8], p[9]),   c1 = cvtpk(p[10], p[11]);
      unsigned d0 = cvtpk(p[12], p[13]), d1 = cvtpk(p[14], p[15]);
      plswap(c0, d0); plswap(c1, d1);
      union { unsigned u[4]; bf16x8 v; } x, y;
      x.u[0] = a0; x.u[1] = a1; x.u[2] = b0; x.u[3] = b1;   // kv +0..15
      y.u[0] = c0; y.u[1] = c1; y.u[2] = d0; y.u[3] = d1;   // kv +16..31
      pa1 = x.v; pa2 = y.v;
    }
    const bf16x8 vb0 = *(const bf16x8*)(sV + ((hi)*32 + l31) * 8);
    const bf16x8 vb1 = *(const bf16x8*)(sV + ((2 + hi) * 32 + l31) * 8);
    accO = __builtin_amdgcn_mfma_f32_32x32x16_bf16(pa1, vb0, accO, 0, 0, 0);
    accO = __builtin_amdgcn_mfma_f32_32x32x16_bf16(pa2, vb1, accO, 0, 0, 0);
    lacc = __builtin_amdgcn_mfma_f32_32x32x16_bf16(pa1, ones, lacc, 0, 0, 0);
    lacc = __builtin_amdgcn_mfma_f32_32x32x16_bf16(pa2, ones, lacc, 0, 0, 0);
    // kv block 1 (kv 32..63 of tile)
#pragma unroll
    for (int r = 0; r < 16; ++r) p[r] = exp2_(s1[r]);
    bf16x8 pa3, pa4;
    {
      unsigned a0 = cvtpk(p[0], p[1]),   a1 = cvtpk(p[2], p[3]);
      unsigned b0 = cvtpk(p[4], p[5]),   b1 = cvtpk(p[6], p[7]);
      plswap(a0, b0); plswap(a1, b1);
      unsigned c0 = cvtpk(p[8], p[9]),   c1 = cvtpk(p[10], p[11]);
      unsigned d0 = cvtpk(p[12], p[13]), d1 = cvtpk(p[14], p[15]);
      plswap(c0, d0); plswap(c1, d1);
      union { unsigned u[4]; bf16x8 v; } x, y;
      x.u[0] = a0; x.u[1] = a1; x.u[2] = b0; x.u[3] = b1;
      y.u[0] = c0; y.u[1] = c1; y.u[2] = d0; y.u[3] = d1;
      pa3 = x.v; pa4 = y.v;
    }
    const bf16x8 vb2 = *(const bf16x8*)(sV + ((4 + hi) * 32 + l31) * 8);
    const bf16x8 vb3 = *(const bf16x8*)(sV + ((6 + hi) * 32 + l31) * 8);
    accO = __builtin_amdgcn_mfma_f32_32x32x16_bf16(pa3, vb2, accO, 0, 0, 0);
    accO = __builtin_amdgcn_mfma_f32_32x32x16_bf16(pa4, vb3, accO, 0, 0, 0);
    lacc = __builtin_amdgcn_mfma_f32_32x32x16_bf16(pa3, ones, lacc, 0, 0, 0);
    lacc = __builtin_amdgcn_mfma_f32_32x32x16_bf16(pa4, ones, lacc, 0, 0, 0);
  }
  // epilogue: unnormalized partial O (bf16) + row-sums (f32)
  short* OP = part == 0 ? OP0 : (part == 1 ? OP1 : (part == 2 ? OP2 : OP3));
#pragma unroll
  for (int r = 0; r < 16; ++r) {
    int qq = (r & 3) + 8 * (r >> 2) + 4 * hi;
    int m = b * SS + qbase + qq;
    OP[(size_t)m * SH + h * HD + l31] = f2bf(accO[r]);
    if (l31 == 0) Lp[((size_t)part * 16 + bh) * SS + qbase + qq] = lacc[r];
  }
}

// ---- 7. combine 4 partials: Ow = sum(Oi) / sum(li), in-place over OP0 ----
__global__ __launch_bounds__(256) void combine_kernel(const short* __restrict__ P0,
    const short* __restrict__ P1, const short* __restrict__ P2,
    const short* __restrict__ P3, const float* __restrict__ Lp,
    short* __restrict__ Ow) {
  int t = blockIdx.x * 256 + threadIdx.x;        // < 524288
  int m = t >> 6, c4 = (t & 63) * 4;
  int b = m >> 12, s = m & 4095, h = c4 >> 5;
  s16x4 o0 = *(const s16x4*)(P0 + (size_t)m * SH + c4);
  s16x4 o1 = *(const s16x4*)(P1 + (size_t)m * SH + c4);
  s16x4 o2 = *(const s16x4*)(P2 + (size_t)m * SH + c4);
  s16x4 o3 = *(const s16x4*)(P3 + (size_t)m * SH + c4);
  int bh = b * 8 + h;
  float l = Lp[(size_t)bh * SS + s] + Lp[((size_t)16 + bh) * SS + s]
          + Lp[((size_t)32 + bh) * SS + s] + Lp[((size_t)48 + bh) * SS + s];
  float rcp = 1.f / l;
  s16x4 out;
#pragma unroll
  for (int j = 0; j < 4; ++j)
    out[j] = f2bf((bf2f(o0[j]) + bf2f(o1[j]) + bf2f(o2[j]) + bf2f(o3[j])) * rcp);
  *(s16x4*)(Ow + (size_t)m * SH + c4) = out;
}

// ---- host ----
extern "C" void kernel_launch(void* const* d_in, const int* in_sizes, int n_in,
                              void* d_out, int out_size, void* d_ws, size_t ws_size,
                              hipStream_t stream) {
  (void)in_sizes; (void)n_in; (void)out_size;
  if (ws_size < WS_NEED) return;
  const float* x  = (const float*)d_in[0];
  const unsigned char* mask = (const unsigned char*)d_in[1];
  const float* wq = (const float*)d_in[2];
  const float* bq = (const float*)d_in[3];
  const float* wk = (const float*)d_in[4];
  const float* bk = (const float*)d_in[5];
  const float* wv = (const float*)d_in[6];
  const float* bv = (const float*)d_in[7];
  const float* wo = (const float*)d_in[8];
  const float* bo = (const float*)d_in[9];
  char* ws = (char*)d_ws;
  int*   cnts    = (int*)(ws + OFF_CNT);
  short* xb      = (short*)(ws + OFF_XB);
  short* Wqkv    = (short*)(ws + OFF_WQKV);
  float* bqkv    = (float*)(ws + OFF_BQKV);
  short* wob     = (short*)(ws + OFF_WOB);
  float* bof     = (float*)(ws + OFF_BO);
  short* Qw      = (short*)(ws + OFF_Q);
  short* Kw      = (short*)(ws + OFF_K);
  short* Vw      = (short*)(ws + OFF_V);
  short* Vtw     = (short*)(ws + OFF_VT);
  // overlays (lifetimes verified):
  short* Kc      = (short*)(ws + OFF_XB);             // xb dead after gemm<0>
  int*   idxC    = (int*)(ws + OFF_WQKV);             // Wqkv dead after gemm<0>
  float* biasC   = (float*)(ws + OFF_WQKV + 65536);   // 32KB idx + 32KB bias < 384KB
  short* OP0     = (short*)(ws + OFF_K);              // K dead after gather
  short* OP1     = (short*)(ws + OFF_V);              // V dead after transpose
  short* OP2     = (short*)(ws + OFF_OP2);            // fresh
  short* OP3     = (short*)(ws + OFF_OP3);            // fresh
  float* Lp      = (float*)(ws + OFF_O);              // f32[4][16][4096] = 1MB

  prep_kernel<<<9220, 256, 0, stream>>>(x, wq, bq, wk, bk, wv, bv, wo, bo,
                                        xb, Wqkv, bqkv, wob, bof);
  gemm_kernel<0><<<dim3(64, 12), 256, 0, stream>>>(xb, Wqkv, bqkv, Qw, Kw, Vw, nullptr);
  scan_mask_kernel<<<2, 256, 0, stream>>>(mask, idxC, biasC, cnts);
  gather_k_kernel<<<dim3(64, 16), 256, 0, stream>>>(Kw, idxC, cnts, Kc);
  transpose_v_kernel<<<dim3(16, 64), 256, 0, stream>>>(Vw, idxC, cnts, Vtw);
  attn_kernel<<<dim3(32, 16, NSPL), 256, 0, stream>>>(Qw, Kc, Vtw, biasC, cnts,
                                                      OP0, OP1, OP2, OP3, Lp);
  combine_kernel<<<2048, 256, 0, stream>>>(OP0, OP1, OP2, OP3, Lp, OP0);
  gemm_kernel<1><<<dim3(64, 4), 256, 0, stream>>>(OP0, wob, bof,
                                                  nullptr, nullptr, nullptr, (float*)d_out);
}

// Round 6
// 90.462 us; speedup vs baseline: 1.0779x; 1.0779x over previous
//
#include <hip/hip_runtime.h>

#define DEV __device__ __forceinline__

typedef __attribute__((ext_vector_type(8)))  short bf16x8;
typedef __attribute__((ext_vector_type(4)))  short s16x4;
typedef __attribute__((ext_vector_type(16))) float f32x16;

constexpr int SB = 2;            // batch
constexpr int SS = 4096;         // seq len
constexpr int SH = 256;          // hidden
constexpr int NHEAD = 8, HD = 32;
constexpr int M_TOK = SB * SS;   // 8192 token rows
constexpr int NQKV = 3 * SH;     // 768

// ---- workspace layout (bytes) ----
constexpr size_t OFF_CNT  = 0;                                 // int[2] padded counts
constexpr size_t OFF_BIAS = 256;                               // spare
constexpr size_t OFF_XB   = OFF_BIAS + 32768;                  // bf16[8192*256]; later Kc
constexpr size_t OFF_WQKV = OFF_XB + (size_t)M_TOK * SH * 2;   // bf16[768*256]; later idxC/biasC
constexpr size_t OFF_BQKV = OFF_WQKV + (size_t)NQKV * SH * 2;  // f32[768] (pad 4096)
constexpr size_t OFF_WOB  = OFF_BQKV + 4096;                   // bf16[256*256]
constexpr size_t OFF_BO   = OFF_WOB + (size_t)SH * SH * 2;     // f32[256] (pad 1024)
constexpr size_t OFF_Q    = OFF_BO + 1024;                     // bf16 [16][4096][32]
constexpr size_t OFF_K    = OFF_Q + (size_t)M_TOK * SH * 2;    // K; later OP0/Ow
constexpr size_t OFF_V    = OFF_K + (size_t)M_TOK * SH * 2;    // V row-major; later OP1
constexpr size_t OFF_VT   = OFF_V + (size_t)M_TOK * SH * 2;    // bf16 [16][32][4096] (compacted)
constexpr size_t OFF_O    = OFF_VT + (size_t)M_TOK * SH * 2;   // f32 Lp[2][16][4096] (512KB of 4MB)
constexpr size_t WS_NEED  = OFF_O + (size_t)M_TOK * SH * 2;

// ---- helpers ----
DEV short f2bf(float f) {                      // RNE f32 -> bf16 bits
  unsigned u = __builtin_bit_cast(unsigned, f);
  u = (u + 0x7FFFu + ((u >> 16) & 1u)) >> 16;
  return (short)u;
}

DEV float bf2f(short s) {
  return __builtin_bit_cast(float, ((unsigned)(unsigned short)s) << 16);
}

DEV float exp2_(float x) {
#if __has_builtin(__builtin_amdgcn_exp2f)
  return __builtin_amdgcn_exp2f(x);
#else
  float r;
  asm("v_exp_f32 %0, %1\n\ts_nop 0" : "=v"(r) : "v"(x));
  return r;
#endif
}

DEV unsigned cvtpk(float lo, float hi) {       // {bf16(lo), bf16(hi)} packed
  unsigned r;
  asm("v_cvt_pk_bf16_f32 %0, %1, %2" : "=v"(r) : "v"(lo), "v"(hi));
  return r;
}

DEV void plswap(unsigned& a, unsigned& b) {    // v_permlane32_swap_b32 a, b
  asm("v_permlane32_swap_b32 %0, %1" : "+v"(a), "+v"(b));
}

// ---- 1. weight/activation prep, vectorized x8 ----
__global__ void prep_kernel(const float* __restrict__ x,
    const float* __restrict__ wq, const float* __restrict__ bq,
    const float* __restrict__ wk, const float* __restrict__ bk,
    const float* __restrict__ wv, const float* __restrict__ bv,
    const float* __restrict__ wo, const float* __restrict__ bo,
    short* __restrict__ xb, short* __restrict__ Wqkv, float* __restrict__ bqkv,
    short* __restrict__ wob, float* __restrict__ bof) {
  const float QS = (float)(1.4426950408889634 / 5.656854249492381);  // log2(e)/sqrt(32)
  long i = ((long)blockIdx.x * 256 + threadIdx.x) * 8;
  const long NX = (long)M_TOK * SH;
  const long NW = (long)NQKV * SH;
  if (i < NX) {
    const float4* s = (const float4*)(x + i);
    float4 f0 = s[0], f1 = s[1];
    bf16x8 o;
    o[0]=f2bf(f0.x); o[1]=f2bf(f0.y); o[2]=f2bf(f0.z); o[3]=f2bf(f0.w);
    o[4]=f2bf(f1.x); o[5]=f2bf(f1.y); o[6]=f2bf(f1.z); o[7]=f2bf(f1.w);
    *(bf16x8*)(xb + i) = o;
    return;
  }
  i -= NX;
  if (i < NW) {
    int n = (int)(i >> 8), kk = (int)(i & 255);
    int tn = n >> 8, rr = n & 255;
    const float* src = (tn == 0 ? wq : (tn == 1 ? wk : wv)) + rr * 256 + kk;
    float sc = tn == 0 ? QS : 1.f;
    float4 f0 = *(const float4*)src, f1 = *(const float4*)(src + 4);
    bf16x8 o;
    o[0]=f2bf(f0.x*sc); o[1]=f2bf(f0.y*sc); o[2]=f2bf(f0.z*sc); o[3]=f2bf(f0.w*sc);
    o[4]=f2bf(f1.x*sc); o[5]=f2bf(f1.y*sc); o[6]=f2bf(f1.z*sc); o[7]=f2bf(f1.w*sc);
    *(bf16x8*)(Wqkv + i) = o;
    return;
  }
  i -= NW;
  if (i < NQKV) {
    int n = (int)i;
#pragma unroll
    for (int j = 0; j < 8; ++j) {
      int nn = n + j, tn = nn >> 8, rr = nn & 255;
      const float* src = tn == 0 ? bq : (tn == 1 ? bk : bv);
      bqkv[nn] = src[rr] * (tn == 0 ? QS : 1.f);
    }
    return;
  }
  i -= NQKV;
  if (i < (long)SH * SH) {
    const float4* s = (const float4*)(wo + i);
    float4 f0 = s[0], f1 = s[1];
    bf16x8 o;
    o[0]=f2bf(f0.x); o[1]=f2bf(f0.y); o[2]=f2bf(f0.z); o[3]=f2bf(f0.w);
    o[4]=f2bf(f1.x); o[5]=f2bf(f1.y); o[6]=f2bf(f1.z); o[7]=f2bf(f1.w);
    *(bf16x8*)(wob + i) = o;
    return;
  }
  i -= (long)SH * SH;
  if (i < SH) {
#pragma unroll
    for (int j = 0; j < 8; ++j) bof[i + j] = bo[i + j];
  }
}

// ---- 2/7. GEMM  C[m,n] = sum_k A[m,k]*B[n,k] + bias[n] ----
template <int MODE>
__global__ __launch_bounds__(256) void gemm_kernel(
    const short* __restrict__ Ag, const short* __restrict__ Bg,
    const float* __restrict__ bias,
    short* __restrict__ q, short* __restrict__ k, short* __restrict__ v,
    float* __restrict__ outf) {
  __shared__ __align__(16) short lA[8192];   // granule-major [kg 0..7][m 0..127] x8
  __shared__ __align__(16) short lB[4096];   // [kg 0..7][n 0..63] x8
  const int tid = threadIdx.x;
  const int lane = tid & 63, w = tid >> 6;
  const int wm = w >> 1, wn = w & 1;
  const int hi = lane >> 5, l31 = lane & 31;
  const int mb = blockIdx.x, nb = blockIdx.y;
  f32x16 acc0, acc1;
#pragma unroll
  for (int i = 0; i < 16; ++i) { acc0[i] = 0.f; acc1[i] = 0.f; }
  bf16x8 ra[4], rb[2];
  const int am = tid >> 3, ak = tid & 7;
  auto gload = [&](int kb) {
#pragma unroll
    for (int p = 0; p < 4; ++p)
      ra[p] = *(const bf16x8*)(Ag + (size_t)(mb * 128 + p * 32 + am) * 256 + kb * 64 + ak * 8);
#pragma unroll
    for (int p = 0; p < 2; ++p)
      rb[p] = *(const bf16x8*)(Bg + (size_t)(nb * 64 + p * 32 + am) * 256 + kb * 64 + ak * 8);
  };
  gload(0);
  for (int kb = 0; kb < 4; ++kb) {
    __syncthreads();
#pragma unroll
    for (int p = 0; p < 4; ++p)
      *(bf16x8*)(lA + (ak * 128 + p * 32 + am) * 8) = ra[p];
#pragma unroll
    for (int p = 0; p < 2; ++p)
      *(bf16x8*)(lB + (ak * 64 + p * 32 + am) * 8) = rb[p];
    __syncthreads();
    if (kb < 3) gload(kb + 1);
#pragma unroll
    for (int ks = 0; ks < 4; ++ks) {
      bf16x8 af0 = *(const bf16x8*)(lA + ((2 * ks + hi) * 128 + wm * 64 + l31) * 8);
      bf16x8 af1 = *(const bf16x8*)(lA + ((2 * ks + hi) * 128 + wm * 64 + 32 + l31) * 8);
      bf16x8 bf  = *(const bf16x8*)(lB + ((2 * ks + hi) * 64 + wn * 32 + l31) * 8);
      acc0 = __builtin_amdgcn_mfma_f32_32x32x16_bf16(af0, bf, acc0, 0, 0, 0);
      acc1 = __builtin_amdgcn_mfma_f32_32x32x16_bf16(af1, bf, acc1, 0, 0, 0);
    }
  }
  const int ncol = nb * 64 + wn * 32 + l31;
  const float bval = bias[ncol];
  if (MODE == 0) {
    const int tensor = nb >> 2;                       // 0=Q 1=K 2=V
    short* dst = tensor == 0 ? q : (tensor == 1 ? k : v);
    const int a = (nb & 3) * 64 + wn * 32 + l31;
    const int hh = a >> 5, d = a & 31;
#pragma unroll
    for (int mt = 0; mt < 2; ++mt) {
      const f32x16& acc = mt == 0 ? acc0 : acc1;
#pragma unroll
      for (int r = 0; r < 16; ++r) {
        int gm = mb * 128 + wm * 64 + mt * 32 + (r & 3) + 8 * (r >> 2) + 4 * hi;
        int bb = gm >> 12, ss = gm & 4095;
        dst[(((size_t)bb * NHEAD + hh) * SS + ss) * HD + d] = f2bf(acc[r] + bval);
      }
    }
  } else {
#pragma unroll
    for (int mt = 0; mt < 2; ++mt) {
      const f32x16& acc = mt == 0 ? acc0 : acc1;
#pragma unroll
      for (int r = 0; r < 16; ++r) {
        int gm = mb * 128 + wm * 64 + mt * 32 + (r & 3) + 8 * (r >> 2) + 4 * hi;
        outf[(size_t)gm * SH + ncol] = acc[r] + bval;
      }
    }
  }
}

// ---- 3. mask scan: detect encoding, stable prefix-scan -> compacted index list ----
// pads count to multiple of 256 so NSPL=2 halves stay multiples of 128
__global__ void scan_mask_kernel(const unsigned char* __restrict__ m,
                                 int* __restrict__ idxC, float* __restrict__ biasC,
                                 int* __restrict__ cnts) {
  __shared__ int f_mis, f_off4, f_3f;
  __shared__ int ts[256];
  const int tid = threadIdx.x, b = blockIdx.x;
  if (tid == 0) { f_mis = 0; f_off4 = 0; f_3f = 0; }
  __syncthreads();
  int lm = 0, lo4 = 0, l3f = 0;
  for (int i = tid; i < 8192; i += 256) {
    unsigned char c = m[i];
    if (c) {
      if (i & 3) lm = 1;
      if ((i & 7) == 4) lo4 = 1;
      if ((i & 3) == 3 && c == 0x3F) l3f = 1;
    }
  }
  if (lm)  atomicOr(&f_mis, 1);
  if (lo4) atomicOr(&f_off4, 1);
  if (l3f) atomicOr(&f_3f, 1);
  __syncthreads();
  const int f = !f_mis ? (f_off4 ? 1 : 3) : (f_3f ? 2 : 0);  // 0=u8 1=i32 2=f32 3=i64
  int bits = 0;
  const int rbase = b * 4096 + tid * 16;
#pragma unroll
  for (int j = 0; j < 16; ++j) {
    int r = rbase + j;
    bool on;
    if (f == 0)      on = m[r] != 0;
    else if (f == 1) on = m[(size_t)r * 4] != 0;
    else if (f == 2) on = m[(size_t)r * 4 + 3] != 0;
    else             on = m[(size_t)r * 8] != 0;
    bits |= (int)on << j;
  }
  const int cnt = __popc(bits);
  ts[tid] = cnt;
  __syncthreads();
  for (int off = 1; off < 256; off <<= 1) {
    int u = (tid >= off) ? ts[tid - off] : 0;
    __syncthreads();
    ts[tid] += u;
    __syncthreads();
  }
  const int total = ts[255];
  int pos = ts[tid] - cnt;   // exclusive
  int* idxB = idxC + b * 4096;
  float* biasB = biasC + b * 4096;
  if (total == 0) {
    // all masked: softmax is shift-invariant -> identical to unmasked softmax
    for (int j = tid; j < 4096; j += 256) { idxB[j] = j; biasB[j] = 0.f; }
    if (tid == 0) cnts[b] = 4096;
    return;
  }
#pragma unroll
  for (int j = 0; j < 16; ++j)
    if ((bits >> j) & 1) { idxB[pos] = tid * 16 + j; biasB[pos] = 0.f; ++pos; }
  int cntpad = (total + 255) & ~255;
  if (cntpad < 256) cntpad = 256;
  for (int j = total + tid; j < cntpad; j += 256) { idxB[j] = -1; biasB[j] = -100000.f; }
  if (tid == 0) cnts[b] = cntpad;
}

// ---- 4. fused gather-K + gather-transpose-V: one idx read, Kc + Vt out ----
__global__ __launch_bounds__(256) void gather_kv_kernel(const short* __restrict__ K,
    const short* __restrict__ V, const int* __restrict__ idxC, const int* __restrict__ cnts,
    short* __restrict__ Kc, short* __restrict__ Vt) {
  const int bh = blockIdx.y, b = bh >> 3;
  const int jb = blockIdx.x * 64;
  if (jb >= cnts[b]) return;
  __shared__ short t[64][33];
  const int tid = threadIdx.x;
  const int s = tid >> 2, g = tid & 3;
  const int ix = idxC[b * 4096 + jb + s];
  bf16x8 kvv{}, vvv{};
  if (ix >= 0) {
    kvv = *(const bf16x8*)(K + ((size_t)bh * SS + ix) * HD + g * 8);
    vvv = *(const bf16x8*)(V + ((size_t)bh * SS + ix) * HD + g * 8);
  }
  *(bf16x8*)(Kc + ((size_t)bh * SS + jb + s) * HD + g * 8) = kvv;
#pragma unroll
  for (int j = 0; j < 8; ++j) t[s][g * 8 + j] = vvv[j];
  __syncthreads();
  const int d = tid >> 3, gs = tid & 7;
  bf16x8 out;
#pragma unroll
  for (int j = 0; j < 8; ++j) out[j] = t[gs * 8 + j][d];
  *(bf16x8*)(Vt + ((size_t)bh * HD + d) * SS + jb + gs * 8) = out;
}

// ---- 5. flash attention over compacted kv, split x2, KVBLK=128 ----
// Same verified sync skeleton (barrier; ds_write; barrier; prefetch; compute);
// tile width doubled -> barrier events halved. NSPL=2 (halves are x128).
__global__ __launch_bounds__(256, 4) void attn_kernel(const short* __restrict__ Q,
    const short* __restrict__ Kc, const short* __restrict__ Vt,
    const float* __restrict__ biasC, const int* __restrict__ cnts,
    short* __restrict__ OP0, short* __restrict__ OP1, float* __restrict__ Lp) {
  __shared__ __align__(16) short sK[4096];   // [gd 0..3][kv 0..127] x8
  __shared__ __align__(16) short sV[4096];   // [gkv 0..15][d 0..31] x8
  __shared__ __align__(16) float sB[128];
  const int tid = threadIdx.x;
  const int lane = tid & 63, wave = tid >> 6;
  const int hi = lane >> 5, l31 = lane & 31;
  const int qblk = blockIdx.x, bh = blockIdx.y, half = blockIdx.z;
  const int b = bh >> 3, h = bh & 7;
  const int Lh = cnts[b] >> 1;          // multiple of 128
  const int NIT = Lh >> 7;
  const int kv0 = half * Lh;
  const short* Kb = Kc + ((size_t)bh * SS + kv0) * HD;
  const short* Vb = Vt + (size_t)bh * HD * SS + kv0;
  const float* biasB = biasC + b * SS + kv0;
  const int qbase = qblk * 128 + wave * 32;
  const short* Qrow = Q + ((size_t)bh * SS + qbase + l31) * HD;
  const bf16x8 qf0 = *(const bf16x8*)(Qrow + hi * 8);
  const bf16x8 qf1 = *(const bf16x8*)(Qrow + 16 + hi * 8);
  bf16x8 ones;
#pragma unroll
  for (int j = 0; j < 8; ++j) ones[j] = (short)0x3F80;   // bf16 1.0
  f32x16 accO, lacc;
#pragma unroll
  for (int i = 0; i < 16; ++i) { accO[i] = 0.f; lacc[i] = 0.f; }
  // staging roles: each thread stages 2 K granules (rows kvs, kvs+64) and
  // 2 V granules (kv-cols gkv*8, 64+gkv*8)
  const int kvs = tid >> 2, gd = tid & 3;
  const int dv = tid >> 3, gkv = tid & 7;
  const short* kvsrc = Kb + (size_t)kvs * HD + gd * 8;
  const short* vvsrc = Vb + (size_t)dv * SS + gkv * 8;
  short* kdst0 = sK + ((size_t)gd * 128 + kvs) * 8;
  short* kdst1 = sK + ((size_t)gd * 128 + 64 + kvs) * 8;
  short* vdst0 = sV + ((size_t)gkv * 32 + dv) * 8;
  short* vdst1 = sV + ((size_t)(gkv + 8) * 32 + dv) * 8;
  bf16x8 stgK0 = *(const bf16x8*)kvsrc;
  bf16x8 stgK1 = *(const bf16x8*)(kvsrc + 64 * HD);
  bf16x8 stgV0 = *(const bf16x8*)vvsrc;
  bf16x8 stgV1 = *(const bf16x8*)(vvsrc + 64);
  float stgb = (tid < 128) ? biasB[tid] : 0.f;

  for (int kt = 0; kt < NIT; ++kt) {
    __syncthreads();
    *(bf16x8*)kdst0 = stgK0;
    *(bf16x8*)kdst1 = stgK1;
    *(bf16x8*)vdst0 = stgV0;
    *(bf16x8*)vdst1 = stgV1;
    if (tid < 128) sB[tid] = stgb;
    __syncthreads();
    if (kt + 1 < NIT) {
      const short* ks = kvsrc + (size_t)(kt + 1) * 128 * HD;
      stgK0 = *(const bf16x8*)ks;
      stgK1 = *(const bf16x8*)(ks + 64 * HD);
      const short* vs = vvsrc + (kt + 1) * 128;
      stgV0 = *(const bf16x8*)vs;
      stgV1 = *(const bf16x8*)(vs + 64);
      if (tid < 128) stgb = biasB[(kt + 1) * 128 + tid];
    }
#pragma unroll
    for (int sub = 0; sub < 2; ++sub) {
      const int kb = sub * 64;
      // C-init scores with mask bias (masked/pad -> -1e5 -> exp2 == 0)
      const float4* bp4 = (const float4*)(sB + kb);
      f32x16 s0, s1;
#pragma unroll
      for (int qd = 0; qd < 4; ++qd) {
        float4 f0 = bp4[2 * qd + hi];
        float4 f1 = bp4[8 + 2 * qd + hi];
        s0[4 * qd + 0] = f0.x; s0[4 * qd + 1] = f0.y; s0[4 * qd + 2] = f0.z; s0[4 * qd + 3] = f0.w;
        s1[4 * qd + 0] = f1.x; s1[4 * qd + 1] = f1.y; s1[4 * qd + 2] = f1.z; s1[4 * qd + 3] = f1.w;
      }
      const bf16x8 a00 = *(const bf16x8*)(sK + ((hi)*128 + kb + l31) * 8);
      const bf16x8 a01 = *(const bf16x8*)(sK + ((2 + hi) * 128 + kb + l31) * 8);
      const bf16x8 a10 = *(const bf16x8*)(sK + ((hi)*128 + kb + 32 + l31) * 8);
      const bf16x8 a11 = *(const bf16x8*)(sK + ((2 + hi) * 128 + kb + 32 + l31) * 8);
      s0 = __builtin_amdgcn_mfma_f32_32x32x16_bf16(a00, qf0, s0, 0, 0, 0);
      s0 = __builtin_amdgcn_mfma_f32_32x32x16_bf16(a01, qf1, s0, 0, 0, 0);
      s1 = __builtin_amdgcn_mfma_f32_32x32x16_bf16(a10, qf0, s1, 0, 0, 0);
      s1 = __builtin_amdgcn_mfma_f32_32x32x16_bf16(a11, qf1, s1, 0, 0, 0);
      // kv block 0 (kv kb+0..31)
      f32x16 p;
#pragma unroll
      for (int r = 0; r < 16; ++r) p[r] = exp2_(s0[r]);
      bf16x8 pa1, pa2;
      {
        unsigned a0 = cvtpk(p[0], p[1]),   a1 = cvtpk(p[2], p[3]);
        unsigned b0 = cvtpk(p[4], p[5]),   b1 = cvtpk(p[6], p[7]);
        plswap(a0, b0); plswap(a1, b1);
        unsigned c0 = cvtpk(p[8], p[9]),   c1 = cvtpk(p[10], p[11]);
        unsigned d0 = cvtpk(p[12], p[13]), d1 = cvtpk(p[14], p[15]);
        plswap(c0, d0); plswap(c1, d1);
        union { unsigned u[4]; bf16x8 v; } x, y;
        x.u[0] = a0; x.u[1] = a1; x.u[2] = b0; x.u[3] = b1;   // kv +0..15
        y.u[0] = c0; y.u[1] = c1; y.u[2] = d0; y.u[3] = d1;   // kv +16..31
        pa1 = x.v; pa2 = y.v;
      }
      const bf16x8 vb0 = *(const bf16x8*)(sV + ((sub * 8 + hi) * 32 + l31) * 8);
      const bf16x8 vb1 = *(const bf16x8*)(sV + ((sub * 8 + 2 + hi) * 32 + l31) * 8);
      accO = __builtin_amdgcn_mfma_f32_32x32x16_bf16(pa1, vb0, accO, 0, 0, 0);
      accO = __builtin_amdgcn_mfma_f32_32x32x16_bf16(pa2, vb1, accO, 0, 0, 0);
      lacc = __builtin_amdgcn_mfma_f32_32x32x16_bf16(pa1, ones, lacc, 0, 0, 0);
      lacc = __builtin_amdgcn_mfma_f32_32x32x16_bf16(pa2, ones, lacc, 0, 0, 0);
      // kv block 1 (kv kb+32..63)
#pragma unroll
      for (int r = 0; r < 16; ++r) p[r] = exp2_(s1[r]);
      bf16x8 pa3, pa4;
      {
        unsigned a0 = cvtpk(p[0], p[1]),   a1 = cvtpk(p[2], p[3]);
        unsigned b0 = cvtpk(p[4], p[5]),   b1 = cvtpk(p[6], p[7]);
        plswap(a0, b0); plswap(a1, b1);
        unsigned c0 = cvtpk(p[8], p[9]),   c1 = cvtpk(p[10], p[11]);
        unsigned d0 = cvtpk(p[12], p[13]), d1 = cvtpk(p[14], p[15]);
        plswap(c0, d0); plswap(c1, d1);
        union { unsigned u[4]; bf16x8 v; } x, y;
        x.u[0] = a0; x.u[1] = a1; x.u[2] = b0; x.u[3] = b1;
        y.u[0] = c0; y.u[1] = c1; y.u[2] = d0; y.u[3] = d1;
        pa3 = x.v; pa4 = y.v;
      }
      const bf16x8 vb2 = *(const bf16x8*)(sV + ((sub * 8 + 4 + hi) * 32 + l31) * 8);
      const bf16x8 vb3 = *(const bf16x8*)(sV + ((sub * 8 + 6 + hi) * 32 + l31) * 8);
      accO = __builtin_amdgcn_mfma_f32_32x32x16_bf16(pa3, vb2, accO, 0, 0, 0);
      accO = __builtin_amdgcn_mfma_f32_32x32x16_bf16(pa4, vb3, accO, 0, 0, 0);
      lacc = __builtin_amdgcn_mfma_f32_32x32x16_bf16(pa3, ones, lacc, 0, 0, 0);
      lacc = __builtin_amdgcn_mfma_f32_32x32x16_bf16(pa4, ones, lacc, 0, 0, 0);
    }
  }
  // epilogue: unnormalized partial O (bf16) + row-sums (f32)
  short* OP = half ? OP1 : OP0;
#pragma unroll
  for (int r = 0; r < 16; ++r) {
    int qq = (r & 3) + 8 * (r >> 2) + 4 * hi;
    int m = b * SS + qbase + qq;
    OP[(size_t)m * SH + h * HD + l31] = f2bf(accO[r]);
    if (l31 == 0) Lp[((size_t)half * 16 + bh) * SS + qbase + qq] = lacc[r];
  }
}

// ---- 6. combine halves: Ow = (O0 + O1) / (l0 + l1), in-place over OP0 ----
__global__ __launch_bounds__(256) void combine_kernel(const short* __restrict__ P0,
    const short* __restrict__ P1, const float* __restrict__ Lp,
    short* __restrict__ Ow) {
  int t = blockIdx.x * 256 + threadIdx.x;        // < 524288
  int m = t >> 6, c4 = (t & 63) * 4;
  int b = m >> 12, s = m & 4095, h = c4 >> 5;
  s16x4 o0 = *(const s16x4*)(P0 + (size_t)m * SH + c4);
  s16x4 o1 = *(const s16x4*)(P1 + (size_t)m * SH + c4);
  int bh = b * 8 + h;
  float l = Lp[(size_t)bh * SS + s] + Lp[((size_t)16 + bh) * SS + s];
  float rcp = 1.f / l;
  s16x4 out;
#pragma unroll
  for (int j = 0; j < 4; ++j) out[j] = f2bf((bf2f(o0[j]) + bf2f(o1[j])) * rcp);
  *(s16x4*)(Ow + (size_t)m * SH + c4) = out;
}

// ---- host ----
extern "C" void kernel_launch(void* const* d_in, const int* in_sizes, int n_in,
                              void* d_out, int out_size, void* d_ws, size_t ws_size,
                              hipStream_t stream) {
  (void)in_sizes; (void)n_in; (void)out_size;
  if (ws_size < WS_NEED) return;
  const float* x  = (const float*)d_in[0];
  const unsigned char* mask = (const unsigned char*)d_in[1];
  const float* wq = (const float*)d_in[2];
  const float* bq = (const float*)d_in[3];
  const float* wk = (const float*)d_in[4];
  const float* bk = (const float*)d_in[5];
  const float* wv = (const float*)d_in[6];
  const float* bv = (const float*)d_in[7];
  const float* wo = (const float*)d_in[8];
  const float* bo = (const float*)d_in[9];
  char* ws = (char*)d_ws;
  int*   cnts    = (int*)(ws + OFF_CNT);
  short* xb      = (short*)(ws + OFF_XB);
  short* Wqkv    = (short*)(ws + OFF_WQKV);
  float* bqkv    = (float*)(ws + OFF_BQKV);
  short* wob     = (short*)(ws + OFF_WOB);
  float* bof     = (float*)(ws + OFF_BO);
  short* Qw      = (short*)(ws + OFF_Q);
  short* Kw      = (short*)(ws + OFF_K);
  short* Vw      = (short*)(ws + OFF_V);
  short* Vtw     = (short*)(ws + OFF_VT);
  // overlays (lifetimes verified):
  short* Kc      = (short*)(ws + OFF_XB);             // xb dead after gemm<0>
  int*   idxC    = (int*)(ws + OFF_WQKV);             // Wqkv dead after gemm<0>
  float* biasC   = (float*)(ws + OFF_WQKV + 65536);   // 32KB idx + 32KB bias < 384KB
  short* OP0     = (short*)(ws + OFF_K);              // K dead after gather
  short* OP1     = (short*)(ws + OFF_V);              // V dead after gather
  float* Lp      = (float*)(ws + OFF_O);              // f32[2][16][4096] = 512KB

  prep_kernel<<<1153, 256, 0, stream>>>(x, wq, bq, wk, bk, wv, bv, wo, bo,
                                        xb, Wqkv, bqkv, wob, bof);
  gemm_kernel<0><<<dim3(64, 12), 256, 0, stream>>>(xb, Wqkv, bqkv, Qw, Kw, Vw, nullptr);
  scan_mask_kernel<<<2, 256, 0, stream>>>(mask, idxC, biasC, cnts);
  gather_kv_kernel<<<dim3(64, 16), 256, 0, stream>>>(Kw, Vw, idxC, cnts, Kc, Vtw);
  attn_kernel<<<dim3(32, 16, 2), 256, 0, stream>>>(Qw, Kc, Vtw, biasC, cnts, OP0, OP1, Lp);
  combine_kernel<<<2048, 256, 0, stream>>>(OP0, OP1, Lp, OP0);
  gemm_kernel<1><<<dim3(64, 4), 256, 0, stream>>>(OP0, wob, bof,
                                                  nullptr, nullptr, nullptr, (float*)d_out);
}